// Round 9
// baseline (299.836 us; speedup 1.0000x reference)
//
#include <hip/hip_runtime.h>
#include <hip/hip_bf16.h>

// Round 9: GEMM rebalanced to be MFMA-bound instead of LDS-bound:
//   64x128 tile with TWO waves (128 thr), wave tile 64x64, BK=64 -> grid
//   stays 800 blocks (3.1/CU) but LDS bytes/FLOP drops ~2x vs R8.
//   Packs vectorized: half4 stores (boundaries 76/476/876 all %4==0).

#define B_SZ     4096
#define LSTM_N   400
#define NG       1600   // 4*LSTM
#define VOCAB    73
#define NATTN    10
#define CHARLEN  64
#define KP1      512    // padded 73+3+400  (mult of 64)
#define KP23     896    // padded 3+400+73+400 (mult of 64)

typedef _Float16 half8 __attribute__((ext_vector_type(8)));
typedef _Float16 half4 __attribute__((ext_vector_type(4)));
typedef __attribute__((ext_vector_type(4))) float floatx4;

__device__ __forceinline__ void gload_lds16(const void* g, void* l) {
    __builtin_amdgcn_global_load_lds(
        (const __attribute__((address_space(1))) void*)g,
        (__attribute__((address_space(3))) void*)l, 16, 0, 0);
}

// [row][64-half] LDS tile, XOR-swizzled 16B granules within each 128B row:
// physical granule = logical granule ^ (row & 7)
__device__ __forceinline__ int lds_off(int r, int g) {
    return (r << 6) + (((g ^ r) & 7) << 3);
}

// ---------------------------------------------------------------- pack weights
// One thread = 4 dest columns (half4 store). z=0: W1 (KP1); z=1/2: W2/W3
// (KP23); z=3: W_attn (KP1, 64 rows). Gate-interleave: dest row n=4u+g.
__global__ __launch_bounds__(256) void pack_wall(const float* __restrict__ Wih1,
                                                 const float* __restrict__ Whh1,
                                                 const float* __restrict__ Wih2,
                                                 const float* __restrict__ Whh2,
                                                 const float* __restrict__ Wih3,
                                                 const float* __restrict__ Whh3,
                                                 const float* __restrict__ W_attn,
                                                 _Float16* __restrict__ W1,
                                                 _Float16* __restrict__ W2,
                                                 _Float16* __restrict__ W3,
                                                 _Float16* __restrict__ Wa)
{
    const int z = blockIdx.z;
    const int n = blockIdx.y;
    const int c = threadIdx.x;          // column group (4 cols)
    float4 v = make_float4(0.f, 0.f, 0.f, 0.f);
    if (z == 3) {
        if (n >= 64 || c >= KP1 / 4) return;
        if (n < 30 && 4 * c < 476) v = *(const float4*)(W_attn + (size_t)n * 476 + 4 * c);
        half4 h = { (_Float16)v.x, (_Float16)v.y, (_Float16)v.z, (_Float16)v.w };
        *(half4*)(Wa + (size_t)n * KP1 + 4 * c) = h;
        return;
    }
    const int u = n >> 2, g = n & 3;
    const int src = g * 400 + u;        // original torch row
    if (z == 0) {
        if (c >= KP1 / 4) return;
        const int k = 4 * c;
        if (k < 76)           v = *(const float4*)(Wih1 + (size_t)src * 76 + k);
        else if (k < 476)     v = *(const float4*)(Whh1 + (size_t)src * 400 + (k - 76));
        half4 h = { (_Float16)v.x, (_Float16)v.y, (_Float16)v.z, (_Float16)v.w };
        *(half4*)(W1 + (size_t)n * KP1 + k) = h;
    } else {
        if (c >= KP23 / 4) return;
        const int k = 4 * c;
        const float* Wih = (z == 1) ? Wih2 : Wih3;
        const float* Whh = (z == 1) ? Whh2 : Whh3;
        if (k < 476)          v = *(const float4*)(Wih + (size_t)src * 476 + k);
        else if (k < 876)     v = *(const float4*)(Whh + (size_t)src * 400 + (k - 476));
        half4 h = { (_Float16)v.x, (_Float16)v.y, (_Float16)v.z, (_Float16)v.w };
        *(half4*)(((z == 1) ? W2 : W3) + (size_t)n * KP23 + k) = h;
    }
}

// ---------------------------------------------------------------- pack X/XA
// One thread = 4 dest columns. Groups: 0..127 -> X1/XA (KP1), 128..351 ->
// X2/X3 (KP23). Scalar reads (w_prev rows are 73 wide, unaligned), half4 store.
__global__ __launch_bounds__(256) void pack_x(const float* __restrict__ w_prev,
                                              const float* __restrict__ inputs,
                                              const float* __restrict__ h1,
                                              const float* __restrict__ h2,
                                              const float* __restrict__ h3,
                                              _Float16* __restrict__ X1,
                                              _Float16* __restrict__ XA,
                                              _Float16* __restrict__ X2,
                                              _Float16* __restrict__ X3)
{
    const int b = blockIdx.y;
    const int c = blockIdx.x * 256 + threadIdx.x;
    if (c < KP1 / 4) {
        float v[4];
#pragma unroll
        for (int j = 0; j < 4; j++) {
            const int k = 4 * c + j;
            float x = 0.f;
            if (k < 73)        x = w_prev[(size_t)b * 73 + k];
            else if (k < 76)   x = inputs[(size_t)b * 3 + (k - 73)];
            else if (k < 476)  x = h1[(size_t)b * 400 + (k - 76)];
            v[j] = x;
        }
        half4 h = { (_Float16)v[0], (_Float16)v[1], (_Float16)v[2], (_Float16)v[3] };
        *(half4*)(X1 + (size_t)b * KP1 + 4 * c) = h;
        // XA h-region [76,476) is overwritten by gemm1's epilogue; skip full groups
        if (c < 19 || c > 118) *(half4*)(XA + (size_t)b * KP1 + 4 * c) = h;
        return;
    }
    const int cc = c - KP1 / 4;
    if (cc >= KP23 / 4) return;
    if (cc >= 1 && cc <= 118) return;   // [4,476) fully written by epilogue/attn
    float v2[4], v3[4];
#pragma unroll
    for (int j = 0; j < 4; j++) {
        const int k = 4 * cc + j;
        float a = 0.f, bq = 0.f;
        if (k < 3) { a = inputs[(size_t)b * 3 + k]; bq = a; }
        else if (k >= 476 && k < 876) {
            a  = h2[(size_t)b * 400 + (k - 476)];
            bq = h3[(size_t)b * 400 + (k - 476)];
        }
        v2[j] = a; v3[j] = bq;
    }
    half4 g2 = { (_Float16)v2[0], (_Float16)v2[1], (_Float16)v2[2], (_Float16)v2[3] };
    half4 g3 = { (_Float16)v3[0], (_Float16)v3[1], (_Float16)v3[2], (_Float16)v3[3] };
    *(half4*)(X2 + (size_t)b * KP23 + 4 * cc) = g2;
    *(half4*)(X3 + (size_t)b * KP23 + 4 * cc) = g3;
}

// ---------------------------------------------------------------- fused GEMM
// 64(m gate rows) x 128(n batch) tile, TWO waves; wave tile 64x64. BK=64.
// Epilogue: lane regs 0..3 = gates i,f,g,o of unit u -> LSTM pointwise.
__global__ __launch_bounds__(128) void gemm_fused(const _Float16* __restrict__ Wm,
                                                  const _Float16* __restrict__ X,
                                                  const float* __restrict__ bias,
                                                  const float* __restrict__ c_in,
                                                  _Float16* __restrict__ d1, int ld1,
                                                  _Float16* __restrict__ d2, int ld2,
                                                  float* __restrict__ fout, int Kp)
{
    __shared__ _Float16 As[64 * 64];    // W tile, 8 KB
    __shared__ _Float16 Bs[128 * 64];   // X tile, 16 KB

    const int t    = threadIdx.x;
    const int w    = t >> 6;            // 0..1
    const int lane = t & 63;
    const int quad = lane >> 4;
    const int l16  = lane & 15;
    const int m0   = blockIdx.y * 64;   // gate-row tile (0..1536)
    const int n0   = blockIdx.x * 128;  // batch tile
    const int wn   = w * 64;            // wave's n half
    const int lr   = lane >> 3;         // 0..7 row-in-8
    const int gq   = (lane & 7) ^ lr;   // logical granule this lane fetches

    floatx4 acc[4][4] = {};

    for (int k0 = 0; k0 < Kp; k0 += 64) {
        __syncthreads();
#pragma unroll
        for (int s = 0; s < 4; s++) {   // A: 64 rows, 4 chunks of 8 per wave
            const int cr = w * 32 + s * 8;
            gload_lds16(Wm + (size_t)(m0 + cr + lr) * Kp + k0 + gq * 8, As + cr * 64);
        }
#pragma unroll
        for (int s = 0; s < 8; s++) {   // B: 128 rows, 8 chunks of 8 per wave
            const int cr = w * 64 + s * 8;
            gload_lds16(X + (size_t)(n0 + cr + lr) * Kp + k0 + gq * 8, Bs + cr * 64);
        }
        asm volatile("s_waitcnt vmcnt(0)" ::: "memory");
        __syncthreads();

#pragma unroll
        for (int h = 0; h < 2; h++) {
            half8 af[4], bf[4];
#pragma unroll
            for (int i = 0; i < 4; i++) {
                af[i] = *(const half8*)(As + lds_off(i * 16 + l16, h * 4 + quad));
                bf[i] = *(const half8*)(Bs + lds_off(wn + i * 16 + l16, h * 4 + quad));
            }
#pragma unroll
            for (int mt = 0; mt < 4; mt++)
#pragma unroll
                for (int nt = 0; nt < 4; nt++)
                    acc[mt][nt] = __builtin_amdgcn_mfma_f32_16x16x32_f16(
                        af[mt], bf[nt], acc[mt][nt], 0, 0, 0);
        }
    }

#pragma unroll
    for (int mt = 0; mt < 4; mt++) {
        const int u = (m0 >> 2) + mt * 4 + quad;           // unit index, < 400
        const float bi  = bias[u];
        const float bff = bias[400 + u];
        const float bg  = bias[800 + u];
        const float bo  = bias[1200 + u];
#pragma unroll
        for (int nt = 0; nt < 4; nt++) {
            const int b = n0 + wn + nt * 16 + l16;         // batch index
            float gi = acc[mt][nt][0] + bi;
            float gf = acc[mt][nt][1] + bff;
            float gg = acc[mt][nt][2] + bg;
            float go = acc[mt][nt][3] + bo;
            float si = 1.f / (1.f + expf(-gi));
            float sf = 1.f / (1.f + expf(-gf));
            float so = 1.f / (1.f + expf(-go));
            float cn = sf * c_in[(size_t)b * LSTM_N + u] + si * tanhf(gg);
            float h  = so * tanhf(cn);
            if (fout) {
                fout[(size_t)b * LSTM_N + u] = h;
            } else {
                _Float16 hh = (_Float16)h;
                d1[(size_t)b * ld1 + u] = hh;
                if (d2) d2[(size_t)b * ld2 + u] = hh;
            }
        }
    }
}

// ---------------------------------------------------------------- plain GEMM
// Attention params: C[b*32 + m] = sum_k Wa[m,k]*XA[b,k] + bias[m], m<30.
// 64x128 tile, 4 waves (small kernel, K=512, grid 32).
__global__ __launch_bounds__(256) void gemm_plain(const _Float16* __restrict__ Wa,
                                                  const _Float16* __restrict__ XA,
                                                  const float* __restrict__ bias,
                                                  float* __restrict__ C, int Kp)
{
    __shared__ _Float16 As[64 * 64];
    __shared__ _Float16 Bs[128 * 64];

    const int t    = threadIdx.x;
    const int w    = t >> 6;
    const int lane = t & 63;
    const int quad = lane >> 4;
    const int l16  = lane & 15;
    const int n0   = blockIdx.x * 128;
    const int wm   = (w >> 1) * 32;
    const int wn   = (w & 1) * 64;
    const int lr   = lane >> 3;
    const int gq   = (lane & 7) ^ lr;

    floatx4 acc[2][4] = {};

    for (int k0 = 0; k0 < Kp; k0 += 64) {
        __syncthreads();
        {
            const int cr = w * 16;
#pragma unroll
            for (int s = 0; s < 2; s++)
                gload_lds16(Wa + (size_t)(cr + s * 8 + lr) * Kp + k0 + gq * 8,
                            As + (cr + s * 8) * 64);
        }
#pragma unroll
        for (int j = 0; j < 2; j++) {
            const int cr = (j * 4 + w) * 16;
#pragma unroll
            for (int s = 0; s < 2; s++)
                gload_lds16(XA + (size_t)(n0 + cr + s * 8 + lr) * Kp + k0 + gq * 8,
                            Bs + (cr + s * 8) * 64);
        }
        asm volatile("s_waitcnt vmcnt(0)" ::: "memory");
        __syncthreads();

#pragma unroll
        for (int h = 0; h < 2; h++) {
            half8 af[2], bf[4];
#pragma unroll
            for (int i = 0; i < 2; i++)
                af[i] = *(const half8*)(As + lds_off(wm + i * 16 + l16, h * 4 + quad));
#pragma unroll
            for (int i = 0; i < 4; i++)
                bf[i] = *(const half8*)(Bs + lds_off(wn + i * 16 + l16, h * 4 + quad));
#pragma unroll
            for (int mt = 0; mt < 2; mt++)
#pragma unroll
                for (int nt = 0; nt < 4; nt++)
                    acc[mt][nt] = __builtin_amdgcn_mfma_f32_16x16x32_f16(
                        af[mt], bf[nt], acc[mt][nt], 0, 0, 0);
        }
    }

#pragma unroll
    for (int mt = 0; mt < 2; mt++) {
#pragma unroll
        for (int r = 0; r < 4; r++) {
            const int m = wm + mt * 16 + quad * 4 + r;
            if (m >= 30) continue;
            const float bv = bias[m];
#pragma unroll
            for (int nt = 0; nt < 4; nt++) {
                const int b = n0 + wn + nt * 16 + l16;
                C[(size_t)b * 32 + m] = acc[mt][nt][r] + bv;
            }
        }
    }
}

// ---------------------------------------------------------------- attn phi+w
// wave = one batch row; 4 waves/block; grid B/4.
__global__ __launch_bounds__(256) void attn_phi(const float* __restrict__ AP,
                                                const float* __restrict__ kappa,
                                                const float* __restrict__ AV,
                                                const int* __restrict__ alen,
                                                _Float16* __restrict__ X2,
                                                _Float16* __restrict__ X3)
{
    __shared__ float prm[4][32];
    __shared__ float phi_s[4][CHARLEN];

    const int t = threadIdx.x;
    const int wave = t >> 6;
    const int lane = t & 63;
    const int b = blockIdx.x * 4 + wave;

    if (lane < 30) {
        float p  = AP[(size_t)b * 32 + lane];
        float sp = (p > 20.f) ? p : log1pf(expf(p));
        float v;
        if (lane < 10)      v = sp;                          // alpha
        else if (lane < 20) v = fmaxf(sp, 0.01f);            // beta
        else                v = kappa[(size_t)b * NATTN + (lane - 20)] + sp * (1.f / 25.f);
        prm[wave][lane] = v;
    }
    __syncthreads();

    const int len = alen[b];
    {
        int c = lane;
        float phi = 0.f;
#pragma unroll
        for (int j = 0; j < NATTN; j++) {
            float d = prm[wave][20 + j] - (float)c;
            phi += prm[wave][j] * expf(-d * d / prm[wave][10 + j]);
        }
        phi_s[wave][c] = (c < len) ? phi : 0.f;
    }
    __syncthreads();

    for (int v0 = 0; v0 < VOCAB; v0 += 64) {   // VOCAB=73 > 64 lanes
        const int v = v0 + lane;
        if (v < VOCAB) {
            const float* avb = AV + (size_t)b * CHARLEN * VOCAB + v;
            float s = 0.f;
            for (int c = 0; c < len; c++)      // len is wave-uniform
                s += phi_s[wave][c] * avb[(size_t)c * VOCAB];
            _Float16 wv = (_Float16)s;
            X2[(size_t)b * KP23 + 403 + v] = wv;
            X3[(size_t)b * KP23 + 403 + v] = wv;
        }
    }
}

// ---------------------------------------------------------------- launch
extern "C" void kernel_launch(void* const* d_in, const int* in_sizes, int n_in,
                              void* d_out, int out_size, void* d_ws, size_t ws_size,
                              hipStream_t stream)
{
    const float* inputs = (const float*)d_in[0];
    const float* h1     = (const float*)d_in[1];
    const float* c1     = (const float*)d_in[2];
    const float* h2     = (const float*)d_in[3];
    const float* c2     = (const float*)d_in[4];
    const float* h3     = (const float*)d_in[5];
    const float* c3     = (const float*)d_in[6];
    const float* kappa  = (const float*)d_in[7];
    const float* w_prev = (const float*)d_in[8];
    const float* AV     = (const float*)d_in[9];
    const int*   alen   = (const int*)d_in[10];
    const float* W_ih1  = (const float*)d_in[11];
    const float* W_hh1  = (const float*)d_in[12];
    const float* b1     = (const float*)d_in[13];
    const float* W_attn = (const float*)d_in[14];
    const float* b_attn = (const float*)d_in[15];
    const float* W_ih2  = (const float*)d_in[16];
    const float* W_hh2  = (const float*)d_in[17];
    const float* b2     = (const float*)d_in[18];
    const float* W_ih3  = (const float*)d_in[19];
    const float* W_hh3  = (const float*)d_in[20];
    const float* b3     = (const float*)d_in[21];
    float* out = (float*)d_out;

    char* p = (char*)d_ws;
    _Float16* X1 = (_Float16*)p; p += (size_t)B_SZ * KP1 * 2;
    _Float16* XA = (_Float16*)p; p += (size_t)B_SZ * KP1 * 2;   // attn input
    _Float16* X2 = (_Float16*)p; p += (size_t)B_SZ * KP23 * 2;
    _Float16* X3 = (_Float16*)p; p += (size_t)B_SZ * KP23 * 2;
    _Float16* W1 = (_Float16*)p; p += (size_t)NG * KP1 * 2;
    _Float16* W2 = (_Float16*)p; p += (size_t)NG * KP23 * 2;
    _Float16* W3 = (_Float16*)p; p += (size_t)NG * KP23 * 2;
    _Float16* Wa = (_Float16*)p; p += (size_t)64 * KP1 * 2;
    float* AP = (float*)p;                                       // B*32 fp32

    pack_wall<<<dim3(1, NG, 4), 256, 0, stream>>>(W_ih1, W_hh1, W_ih2, W_hh2,
                                                  W_ih3, W_hh3, W_attn,
                                                  W1, W2, W3, Wa);
    pack_x<<<dim3(2, B_SZ), 256, 0, stream>>>(w_prev, inputs, h1, h2, h3,
                                              X1, XA, X2, X3);

    const dim3 fgrid(B_SZ / 128, NG / 64);   // 32 batch-tiles x 25 row-tiles

    // LSTM1: h1n -> XA h-region (attn input) + X2 cols 3..
    gemm_fused<<<fgrid, 128, 0, stream>>>(W1, X1, b1, c1,
                                          XA + 76, KP1, X2 + 3, KP23, nullptr, KP1);
    // attention params: AP[b,0:30] = Wa * XA[b] + b_attn
    gemm_plain<<<dim3(B_SZ / 128, 1), 256, 0, stream>>>(Wa, XA, b_attn, AP, KP1);
    // phi + einsum -> w into X2, X3
    attn_phi<<<B_SZ / 4, 256, 0, stream>>>(AP, kappa, AV, alen, X2, X3);
    // LSTM2: h2n -> X3 cols 3..
    gemm_fused<<<fgrid, 128, 0, stream>>>(W2, X2, b2, c2,
                                          X3 + 3, KP23, nullptr, 0, nullptr, KP23);
    // LSTM3: h3n -> out (fp32)
    gemm_fused<<<fgrid, 128, 0, stream>>>(W3, X3, b3, c3,
                                          nullptr, 0, nullptr, 0, out, KP23);
}